// Round 6
// baseline (870.226 us; speedup 1.0000x reference)
//
#include <hip/hip_runtime.h>
#include <hip/hip_bf16.h>

// HiPPO-LegT parallel chunked scan, round 6 (= round-5 design, compile fixed:
// nontemporal store uses ext_vector float4, not HIP_vector_type).
// Entire precompute in ONE persistent kernel (256 blocks = 1/CU, hand-rolled
// monotonic atomic grid barrier), then the split-bf16 MFMA out_gemm with
// non-temporal output stores.
//
// ws layout (floats):
//   P   : A^1..A^64 (slot j-1 = A^j; slot 0 = copy of A)   (64 * 65536)
//   Kv  : A^j B, j=0..63     (64 * 256)
//   e   : scan buffer 0      (64 * 256 * 64)
//   w2  : scan buffer 1      (64 * 256 * 64)
//   MS  : squaring ping-pong (2 * 65536)
//   Ht  : bf16 [4096][640]   (hi 0..319 | lo 320..639)   (ushort)
//   Gt  : bf16 [16384][640]                               (ushort)
//   ctr : 1 unsigned (barrier counter, memset to 0 per call)

#define MATF 65536

typedef __attribute__((ext_vector_type(8))) short short8;
typedef __attribute__((ext_vector_type(4))) float f32x4;

__device__ __forceinline__ unsigned short f2bf(float x) {
  union { __hip_bfloat16 h; unsigned short u; } cv;
  cv.h = __float2bfloat16(x);
  return cv.u;
}
__device__ __forceinline__ float bf2f(unsigned short u) {
  union { unsigned short u; __hip_bfloat16 h; } cv;
  cv.u = u;
  return __bfloat162float(cv.h);
}

__device__ __forceinline__ void load16_lds(const void* gsrc, void* ldst) {
  __builtin_amdgcn_global_load_lds(
      (const __attribute__((address_space(1))) unsigned int*)gsrc,
      (__attribute__((address_space(3))) unsigned int*)ldst,
      16, 0, 0);
}

// 64x64 tile of a 256x256x256 fp32 product Z = X @ Y; 256 threads.
// Ends with __syncthreads() after last LDS read -> safe to chain items.
__device__ void tile_gemm64(const float* __restrict__ X,
                            const float* __restrict__ Y,
                            float* __restrict__ Z, int tile,
                            float* As, float* Bs, int tid)
{
  int tr = (tile >> 2) * 64;
  int tc = (tile & 3) * 64;
  int tx = tid & 15, ty = tid >> 4;
  float acc[4][4] = {};
  for (int k0 = 0; k0 < 256; k0 += 32) {
#pragma unroll
    for (int p = 0; p < 2; ++p) {
      int idx = tid + p * 256;
      int r = idx >> 3, c4 = (idx & 7) * 4;
      float4 v = *(const float4*)(X + (size_t)(tr + r) * 256 + k0 + c4);
      As[r * 33 + c4 + 0] = v.x; As[r * 33 + c4 + 1] = v.y;
      As[r * 33 + c4 + 2] = v.z; As[r * 33 + c4 + 3] = v.w;
    }
#pragma unroll
    for (int p = 0; p < 2; ++p) {
      int idx = tid + p * 256;
      int r = idx >> 4, c4 = (idx & 15) * 4;
      float4 v = *(const float4*)(Y + (size_t)(k0 + r) * 256 + tc + c4);
      Bs[r * 65 + c4 + 0] = v.x; Bs[r * 65 + c4 + 1] = v.y;
      Bs[r * 65 + c4 + 2] = v.z; Bs[r * 65 + c4 + 3] = v.w;
    }
    __syncthreads();
#pragma unroll
    for (int kk = 0; kk < 32; ++kk) {
      float a[4], b[4];
#pragma unroll
      for (int u = 0; u < 4; ++u) a[u] = As[(ty * 4 + u) * 33 + kk];
#pragma unroll
      for (int v = 0; v < 4; ++v) b[v] = Bs[kk * 65 + tx * 4 + v];
#pragma unroll
      for (int u = 0; u < 4; ++u)
#pragma unroll
        for (int v = 0; v < 4; ++v) acc[u][v] += a[u] * b[v];
    }
    __syncthreads();
  }
#pragma unroll
  for (int u = 0; u < 4; ++u)
#pragma unroll
    for (int v = 0; v < 4; ++v)
      Z[(size_t)(tr + ty * 4 + u) * 256 + tc + tx * 4 + v] = acc[u][v];
}

__global__ __launch_bounds__(256, 1) void precompute_persist(
    const float* __restrict__ A, const float* __restrict__ Bv,
    const float* __restrict__ in,
    float* __restrict__ P, float* __restrict__ Kv,
    float* __restrict__ e, float* __restrict__ w2, float* __restrict__ MS,
    unsigned short* __restrict__ Ht, unsigned short* __restrict__ Gt,
    unsigned* ctr)
{
  __shared__ float As[64 * 33];
  __shared__ float Bs[32 * 65];
  int bid = blockIdx.x, tid = threadIdx.x;
  unsigned epoch = 0;

  auto bar = [&]() {
    ++epoch;
    __syncthreads();
    if (tid == 0) {
      __threadfence();
      __hip_atomic_fetch_add(ctr, 1u, __ATOMIC_RELEASE, __HIP_MEMORY_SCOPE_AGENT);
      while (__hip_atomic_load(ctr, __ATOMIC_ACQUIRE, __HIP_MEMORY_SCOPE_AGENT)
             < epoch * 256u)
        __builtin_amdgcn_s_sleep(16);
      __threadfence();
    }
    __syncthreads();
  };

  // ---- phase 0 (t=0): A^2 = A@A ; Kv1 = A@Bv ; P slot0 = A ; Kv0 = Bv ----
  for (int w = bid; w < 34; w += 256) {
    if (w < 16) {
      tile_gemm64(A, A, P + MATF, w, As, Bs, tid);
    } else if (w == 16) {
      __syncthreads();
      Bs[tid] = Bv[tid];
      __syncthreads();
      float acc = 0.f;
      for (int mm = 0; mm < 256; ++mm)
        acc += A[(size_t)tid * 256 + mm] * Bs[mm];
      Kv[256 + tid] = acc;
      __syncthreads();
    } else if (w < 33) {
      int blk = w - 17;
#pragma unroll
      for (int q = 0; q < 4; ++q) {
        int idx = blk * 1024 + q * 256 + tid;
        *(float4*)(P + (size_t)idx * 4) = *(const float4*)(A + (size_t)idx * 4);
      }
    } else {
      Kv[tid] = Bv[tid];
    }
  }
  bar();

  // ---- doubling rounds t=1..5: P_{m+j}=P_m@P_j ; Kv_{m+jj}=P_m@Kv_jj ----
  for (int t = 1; t < 6; ++t) {
    int m = 1 << t;
    for (int w = bid; w < 17 * m; w += 256) {
      if (w < 16 * m) {
        int j = (w >> 4) + 1;
        tile_gemm64(P + (size_t)(m - 1) * MATF, P + (size_t)(j - 1) * MATF,
                    P + (size_t)(m + j - 1) * MATF, w & 15, As, Bs, tid);
      } else {
        int jj = w - 16 * m;
        __syncthreads();
        Bs[tid] = Kv[(size_t)jj * 256 + tid];
        __syncthreads();
        const float* Pm = P + (size_t)(m - 1) * MATF;
        float acc = 0.f;
        for (int mm = 0; mm < 256; ++mm)
          acc += Pm[(size_t)tid * 256 + mm] * Bs[mm];
        Kv[(size_t)(m + jj) * 256 + tid] = acc;
        __syncthreads();
      }
    }
    bar();
  }

  // ---- e phase: e_k[n][b] = sum_j Kv_j[n] * f[k*64+63-j][b] ----
  {
    int k = bid >> 2, bq = bid & 3;
#pragma unroll
    for (int q = 0; q < 4; ++q) {
      int idx = tid + q * 256;
      As[(idx >> 4) * 16 + (idx & 15)] =
          in[(size_t)(k * 64 + (idx >> 4)) * 64 + bq * 16 + (idx & 15)];
    }
    __syncthreads();
    float acc[16] = {};
    for (int j = 0; j < 64; ++j) {
      float kvj = Kv[(size_t)j * 256 + tid];
#pragma unroll
      for (int b2 = 0; b2 < 16; ++b2)
        acc[b2] += kvj * As[(63 - j) * 16 + b2];
    }
#pragma unroll
    for (int b2 = 0; b2 < 16; ++b2)
      e[((size_t)k * 256 + tid) * 64 + bq * 16 + b2] = acc[b2];
    __syncthreads();
  }
  bar();

  // ---- scan rounds r=0..5, fused squaring M_{r+1}=M_r^2 (r<5) ----
  for (int r = 0; r < 6; ++r) {
    int d = 1 << r;
    const float* M = (r == 0) ? (P + (size_t)63 * MATF)
                              : (MS + (size_t)((r - 1) & 1) * MATF);
    const float* src_base = (r & 1) ? w2 : e;
    float* dst_base = (r & 1) ? e : w2;
    int nit = 256 + ((r < 5) ? 16 : 0);
    for (int w = bid; w < nit; w += 256) {
      if (w >= 256) {
        tile_gemm64(M, M, MS + (size_t)(r & 1) * MATF, w - 256, As, Bs, tid);
        continue;
      }
      int k = w >> 2, rt = w & 3;
      const float* src = src_base + (size_t)k * 16384;
      float* dst = dst_base + (size_t)k * 16384;
      if (k < d) {
#pragma unroll
        for (int p = 0; p < 16; ++p) {
          int idx = rt * 4096 + p * 256 + tid;
          dst[idx] = src[idx];
        }
        continue;
      }
      const float* v = src_base + (size_t)(k - d) * 16384;
      int tx = tid & 15, ty = tid >> 4;
      float acc[4][4] = {};
      for (int k0 = 0; k0 < 256; k0 += 32) {
#pragma unroll
        for (int p = 0; p < 2; ++p) {
          int idx = tid + p * 256;
          int rr = idx >> 3, c4 = (idx & 7) * 4;
          float4 t4 = *(const float4*)(M + (size_t)(rt * 64 + rr) * 256 + k0 + c4);
          As[rr * 33 + c4 + 0] = t4.x; As[rr * 33 + c4 + 1] = t4.y;
          As[rr * 33 + c4 + 2] = t4.z; As[rr * 33 + c4 + 3] = t4.w;
        }
#pragma unroll
        for (int p = 0; p < 2; ++p) {
          int idx = tid + p * 256;
          int rr = idx >> 4, c4 = (idx & 15) * 4;
          float4 t4 = *(const float4*)(v + (size_t)(k0 + rr) * 64 + c4);
          Bs[rr * 65 + c4 + 0] = t4.x; Bs[rr * 65 + c4 + 1] = t4.y;
          Bs[rr * 65 + c4 + 2] = t4.z; Bs[rr * 65 + c4 + 3] = t4.w;
        }
        __syncthreads();
#pragma unroll
        for (int kk = 0; kk < 32; ++kk) {
          float a[4], b[4];
#pragma unroll
          for (int u = 0; u < 4; ++u) a[u] = As[(ty * 4 + u) * 33 + kk];
#pragma unroll
          for (int v2 = 0; v2 < 4; ++v2) b[v2] = Bs[kk * 65 + tx * 4 + v2];
#pragma unroll
          for (int u = 0; u < 4; ++u)
#pragma unroll
            for (int v2 = 0; v2 < 4; ++v2) acc[u][v2] += a[u] * b[v2];
        }
        __syncthreads();
      }
#pragma unroll
      for (int u = 0; u < 4; ++u)
#pragma unroll
        for (int v2 = 0; v2 < 4; ++v2) {
          int idx = (rt * 64 + ty * 4 + u) * 64 + tx * 4 + v2;
          dst[idx] = src[idx] + acc[u][v2];
        }
    }
    bar();
  }
  // final scan result in e (round 5 writes e)

  // ---- build Ht (rows 0..4095) and Gt (rows 4096..20479), grid-stride ----
  for (int row = bid; row < 20480; row += 256) {
    for (int c = tid; c < 320; c += 256) {
      float x;
      unsigned short* dst;
      if (row < 4096) {
        int k = row >> 6, b = row & 63;
        x = (c < 64) ? in[(size_t)(k * 64 + c) * 64 + b]
                     : ((k > 0) ? e[((size_t)(k - 1) * 256 + (c - 64)) * 64 + b]
                                : 0.f);
        dst = Ht + (size_t)row * 640;
      } else {
        int r2 = row - 4096;
        int i = r2 >> 8, n = r2 & 255;
        x = (c < 64) ? ((c <= i) ? Kv[(size_t)(i - c) * 256 + n] : 0.f)
                     : P[(size_t)i * MATF + (size_t)n * 256 + (c - 64)];
        dst = Gt + (size_t)r2 * 640;
      }
      unsigned short hi = f2bf(x);
      float lo = x - bf2f(hi);
      dst[c]       = hi;
      dst[320 + c] = f2bf(lo);
    }
  }
}

// ---------- out = Ht @ Gt^T via split-bf16 MFMA; NT output stores ----------
__global__ __launch_bounds__(256) void out_gemm(
    const unsigned short* __restrict__ Ht,
    const unsigned short* __restrict__ Gt,
    float* __restrict__ out)
{
  __shared__ char smem[32768];
  char* Ab = smem;
  char* Bb = smem + 16384;

  int bid = blockIdx.x;
  int swz = (bid & 7) * 512 + (bid >> 3);   // XCD swizzle (4096 % 8 == 0)
  int nt = swz >> 5;
  int mt = swz & 31;
  int mrow0 = mt * 128, nrow0 = nt * 128;

  int tid = threadIdx.x;
  int w = tid >> 6, l = tid & 63;
  int wm = w >> 1, wn = w & 1;

  auto stage = [&](const unsigned short* src, int row0, char* lds, int k0) {
#pragma unroll
    for (int it = 0; it < 4; ++it) {
      int L = it * 4096 + tid * 16;
      int row = L >> 7;
      int p = (L >> 4) & 7;
      int o = p ^ (row & 7);
      int h = o >> 2, q = o & 3;
      const void* g = src + (size_t)(row0 + row) * 640 + h * 320 + k0 + q * 8;
      void* dst = lds + (it * 4096 + w * 1024);
      load16_lds(g, dst);
    }
  };

  stage(Ht, mrow0, Ab, 0);
  stage(Gt, nrow0, Bb, 0);

  f32x4 acc[4][4] = {};
  int rAbase = wm * 64 + (l & 15);
  int rBbase = wn * 64 + (l & 15);
  int qo = l >> 4;

  for (int ks = 0; ks < 10; ++ks) {
    __syncthreads();
    short8 ah[4], al[4], bh[4], bl[4];
#pragma unroll
    for (int mf = 0; mf < 4; ++mf) {
      int r = rAbase + mf * 16;
      int ph = (qo)     ^ (r & 7);
      int pl = (4 + qo) ^ (r & 7);
      ah[mf] = *(const short8*)(Ab + r * 128 + ph * 16);
      al[mf] = *(const short8*)(Ab + r * 128 + pl * 16);
    }
#pragma unroll
    for (int nf = 0; nf < 4; ++nf) {
      int r = rBbase + nf * 16;
      int ph = (qo)     ^ (r & 7);
      int pl = (4 + qo) ^ (r & 7);
      bh[nf] = *(const short8*)(Bb + r * 128 + ph * 16);
      bl[nf] = *(const short8*)(Bb + r * 128 + pl * 16);
    }
    __syncthreads();
    if (ks < 9) {
      stage(Ht, mrow0, Ab, (ks + 1) * 32);
      stage(Gt, nrow0, Bb, (ks + 1) * 32);
    }
#pragma unroll
    for (int mf = 0; mf < 4; ++mf)
#pragma unroll
      for (int nf = 0; nf < 4; ++nf) {
        acc[mf][nf] = __builtin_amdgcn_mfma_f32_16x16x32_bf16(ah[mf], bh[nf], acc[mf][nf], 0, 0, 0);
        acc[mf][nf] = __builtin_amdgcn_mfma_f32_16x16x32_bf16(ah[mf], bl[nf], acc[mf][nf], 0, 0, 0);
        acc[mf][nf] = __builtin_amdgcn_mfma_f32_16x16x32_bf16(al[mf], bh[nf], acc[mf][nf], 0, 0, 0);
      }
  }

  // Epilogue: per-wave LDS transpose -> 256B-contiguous NON-TEMPORAL stores
  // (ext_vector f32x4; bypass write-allocate; output never re-read).
  float* Tw = (float*)(smem + w * 4352);   // 16 rows x 68 floats per wave
  int Mwave = mrow0 + wm * 64;
  int ncol0 = nrow0 + wn * 64;
  int i  = ncol0 >> 8;
  int n0 = ncol0 & 255;
#pragma unroll
  for (int mf = 0; mf < 4; ++mf) {
#pragma unroll
    for (int nf = 0; nf < 4; ++nf)
#pragma unroll
      for (int r = 0; r < 4; ++r)
        Tw[((l >> 4) * 4 + r) * 68 + nf * 16 + (l & 15)] = acc[mf][nf][r];
#pragma unroll
    for (int rr = 0; rr < 4; ++rr) {
      int row16 = rr * 4 + (l >> 4);
      f32x4 v = *(const f32x4*)&Tw[row16 * 68 + (l & 15) * 4];
      int Mrow = Mwave + mf * 16 + row16;
      int k = Mrow >> 6, b = Mrow & 63;
      __builtin_nontemporal_store(
          v, (f32x4*)&out[((size_t)k * 4096 + (size_t)i * 64 + b) * 256 +
                          n0 + (l & 15) * 4]);
    }
  }
}

extern "C" void kernel_launch(void* const* d_in, const int* in_sizes, int n_in,
                              void* d_out, int out_size, void* d_ws, size_t ws_size,
                              hipStream_t stream)
{
  const float* in = (const float*)d_in[0];
  const float* A  = (const float*)d_in[1];
  const float* Bv = (const float*)d_in[2];
  float* out = (float*)d_out;
  float* ws  = (float*)d_ws;

  float* P  = ws;                          // A^1..A^64 (slot0 = A copy)
  float* Kv = P  + (size_t)64 * MATF;
  float* e  = Kv + (size_t)64 * 256;       // scan buf 0
  float* w2 = e  + (size_t)64 * 16384;     // scan buf 1
  float* MS = w2 + (size_t)64 * 16384;     // squaring ping-pong
  unsigned short* Ht = (unsigned short*)(MS + (size_t)2 * MATF);
  unsigned short* Gt = Ht + (size_t)4096 * 640;
  unsigned* ctr = (unsigned*)(Gt + (size_t)16384 * 640);

  (void)hipMemsetAsync(ctr, 0, sizeof(unsigned), stream);
  precompute_persist<<<dim3(256), dim3(256), 0, stream>>>(
      A, Bv, in, P, Kv, e, w2, MS, Ht, Gt, ctr);
  out_gemm<<<dim3(4096), dim3(256), 0, stream>>>(Ht, Gt, out);
}

// Round 7
// 548.135 us; speedup vs baseline: 1.5876x; 1.5876x over previous
//
#include <hip/hip_runtime.h>
#include <hip/hip_bf16.h>

// HiPPO-LegT parallel chunked scan, round 7.
// = R4 structure (fused launches, regular kernels) with the epilogue fixed:
//   - NO LDS transpose in out_gemm epilogue (R4's added 1e6 bank conflicts)
//   - R2-proven direct scatter stores, now NON-TEMPORAL (ext_vector-safe
//     scalar float NT stores) to kill the 294MB TCC write-allocate fetch.
//
// ws layout (floats):
//   P   : A^1..A^64          (64 * 65536)
//   Kv  : A^j B, j=0..63     (64 * 256)
//   e   : scan buffer 0      (64 * 256 * 64)
//   w2  : scan buffer 1      (64 * 256 * 64)
//   MS  : squaring ping-pong (2 * 65536)
//   Ht  : bf16 [4096][640]   (hi 0..319 | lo 320..639)   (ushort)
//   Gt  : bf16 [16384][640]                               (ushort)

#define MATF 65536

typedef __attribute__((ext_vector_type(8))) short short8;
typedef __attribute__((ext_vector_type(4))) float f32x4;

__device__ __forceinline__ unsigned short f2bf(float x) {
  union { __hip_bfloat16 h; unsigned short u; } cv;
  cv.h = __float2bfloat16(x);
  return cv.u;
}
__device__ __forceinline__ float bf2f(unsigned short u) {
  union { unsigned short u; __hip_bfloat16 h; } cv;
  cv.u = u;
  return __bfloat162float(cv.h);
}

__device__ __forceinline__ void load16_lds(const void* gsrc, void* ldst) {
  __builtin_amdgcn_global_load_lds(
      (const __attribute__((address_space(1))) unsigned int*)gsrc,
      (__attribute__((address_space(3))) unsigned int*)ldst,
      16, 0, 0);
}

// 64x64 tile of a 256x256x256 fp32 product Z = X @ Y; 256 threads.
__device__ void tile_gemm64(const float* __restrict__ X,
                            const float* __restrict__ Y,
                            float* __restrict__ Z, int tile,
                            float* As, float* Bs, int tid)
{
  int tr = (tile >> 2) * 64;
  int tc = (tile & 3) * 64;
  int tx = tid & 15, ty = tid >> 4;
  float acc[4][4] = {};
  for (int k0 = 0; k0 < 256; k0 += 32) {
#pragma unroll
    for (int p = 0; p < 2; ++p) {
      int idx = tid + p * 256;
      int r = idx >> 3, c4 = (idx & 7) * 4;
      float4 v = *(const float4*)(X + (size_t)(tr + r) * 256 + k0 + c4);
      As[r * 33 + c4 + 0] = v.x; As[r * 33 + c4 + 1] = v.y;
      As[r * 33 + c4 + 2] = v.z; As[r * 33 + c4 + 3] = v.w;
    }
#pragma unroll
    for (int p = 0; p < 2; ++p) {
      int idx = tid + p * 256;
      int r = idx >> 4, c4 = (idx & 15) * 4;
      float4 v = *(const float4*)(Y + (size_t)(k0 + r) * 256 + tc + c4);
      Bs[r * 65 + c4 + 0] = v.x; Bs[r * 65 + c4 + 1] = v.y;
      Bs[r * 65 + c4 + 2] = v.z; Bs[r * 65 + c4 + 3] = v.w;
    }
    __syncthreads();
#pragma unroll
    for (int kk = 0; kk < 32; ++kk) {
      float a[4], b[4];
#pragma unroll
      for (int u = 0; u < 4; ++u) a[u] = As[(ty * 4 + u) * 33 + kk];
#pragma unroll
      for (int v = 0; v < 4; ++v) b[v] = Bs[kk * 65 + tx * 4 + v];
#pragma unroll
      for (int u = 0; u < 4; ++u)
#pragma unroll
        for (int v = 0; v < 4; ++v) acc[u][v] += a[u] * b[v];
    }
    __syncthreads();
  }
#pragma unroll
  for (int u = 0; u < 4; ++u)
#pragma unroll
    for (int v = 0; v < 4; ++v)
      Z[(size_t)(tr + ty * 4 + u) * 256 + tc + tx * 4 + v] = acc[u][v];
}

// ---------- init: P_1 = A ; Kv_0 = B ----------
__global__ __launch_bounds__(256) void init_kernel(
    const float* __restrict__ A, const float* __restrict__ Bv,
    float* __restrict__ P, float* __restrict__ Kv)
{
  int bid = blockIdx.x, tid = threadIdx.x;
  if (bid < 64) {
    int idx = bid * 256 + tid;
    *(float4*)(P + (size_t)idx * 4) = *(const float4*)(A + (size_t)idx * 4);
  } else {
    Kv[tid] = Bv[tid];
  }
}

// ---------- doubling round: P_{m+j} = P_m @ P_j ; Kv_{m+jj} = P_m @ Kv_jj ----------
__global__ __launch_bounds__(256) void pow_round(
    float* __restrict__ P, float* __restrict__ Kv, int m)
{
  __shared__ float As[64 * 33];
  __shared__ float Bs[32 * 65];
  int bid = blockIdx.x, tid = threadIdx.x;
  if (bid < m * 16) {
    int j = (bid >> 4) + 1;
    tile_gemm64(P + (size_t)(m - 1) * MATF, P + (size_t)(j - 1) * MATF,
                P + (size_t)(m + j - 1) * MATF, bid & 15, As, Bs, tid);
  } else {
    int jj = bid - m * 16;
    Bs[tid] = Kv[(size_t)jj * 256 + tid];
    __syncthreads();
    const float* Pm = P + (size_t)(m - 1) * MATF;
    float acc = 0.f;
    for (int mm = 0; mm < 256; ++mm)
      acc += Pm[(size_t)tid * 256 + mm] * Bs[mm];
    Kv[(size_t)(m + jj) * 256 + tid] = acc;
  }
}

// ---------- e phase: e_k[n][b] = sum_j Kv_j[n] * f[k*64+63-j][b] ----------
__global__ __launch_bounds__(256) void e_kernel(
    const float* __restrict__ in, const float* __restrict__ Kv,
    float* __restrict__ e)
{
  __shared__ float fs[1024];
  int bid = blockIdx.x, tid = threadIdx.x;
  int k = bid >> 2, bq = bid & 3;
#pragma unroll
  for (int q = 0; q < 4; ++q) {
    int idx = tid + q * 256;
    int i = idx >> 4, bb = idx & 15;
    fs[i * 16 + bb] = in[(size_t)(k * 64 + i) * 64 + bq * 16 + bb];
  }
  __syncthreads();
  int n = tid;
  float acc[16] = {};
  for (int j = 0; j < 64; ++j) {
    float kvj = Kv[(size_t)j * 256 + n];
#pragma unroll
    for (int b2 = 0; b2 < 16; ++b2)
      acc[b2] += kvj * fs[(63 - j) * 16 + b2];
  }
#pragma unroll
  for (int b2 = 0; b2 < 16; ++b2)
    e[((size_t)k * 256 + n) * 64 + bq * 16 + b2] = acc[b2];
}

// ---------- scan round + fused squaring ----------
// blocks 0..255: dst[k] = src[k] + M @ src[k-d] ; blocks 256..271: MSdst = M @ M
__global__ __launch_bounds__(256) void scan_round(
    const float* __restrict__ M, float* __restrict__ MSdst,
    const float* __restrict__ src_base, float* __restrict__ dst_base, int d)
{
  __shared__ float As[64 * 33];
  __shared__ float Bs[32 * 65];
  int bid = blockIdx.x, tid = threadIdx.x;
  if (bid >= 256) {
    tile_gemm64(M, M, MSdst, bid - 256, As, Bs, tid);
    return;
  }
  int k = bid >> 2, rt = bid & 3;
  const float* src = src_base + (size_t)k * 16384;
  float*       dst = dst_base + (size_t)k * 16384;
  if (k < d) {
#pragma unroll
    for (int p = 0; p < 16; ++p) {
      int idx = rt * 4096 + p * 256 + tid;
      dst[idx] = src[idx];
    }
    return;
  }
  const float* v = src_base + (size_t)(k - d) * 16384;
  int tx = tid & 15, ty = tid >> 4;
  float acc[4][4] = {};
  for (int k0 = 0; k0 < 256; k0 += 32) {
#pragma unroll
    for (int p = 0; p < 2; ++p) {
      int idx = tid + p * 256;
      int r = idx >> 3, c4 = (idx & 7) * 4;
      float4 t4 = *(const float4*)(M + (size_t)(rt * 64 + r) * 256 + k0 + c4);
      As[r * 33 + c4 + 0] = t4.x; As[r * 33 + c4 + 1] = t4.y;
      As[r * 33 + c4 + 2] = t4.z; As[r * 33 + c4 + 3] = t4.w;
    }
#pragma unroll
    for (int p = 0; p < 2; ++p) {
      int idx = tid + p * 256;
      int r = idx >> 4, c4 = (idx & 15) * 4;
      float4 t4 = *(const float4*)(v + (size_t)(k0 + r) * 64 + c4);
      Bs[r * 65 + c4 + 0] = t4.x; Bs[r * 65 + c4 + 1] = t4.y;
      Bs[r * 65 + c4 + 2] = t4.z; Bs[r * 65 + c4 + 3] = t4.w;
    }
    __syncthreads();
#pragma unroll
    for (int kk = 0; kk < 32; ++kk) {
      float a[4], b[4];
#pragma unroll
      for (int u = 0; u < 4; ++u) a[u] = As[(ty * 4 + u) * 33 + kk];
#pragma unroll
      for (int v2 = 0; v2 < 4; ++v2) b[v2] = Bs[kk * 65 + tx * 4 + v2];
#pragma unroll
      for (int u = 0; u < 4; ++u)
#pragma unroll
        for (int v2 = 0; v2 < 4; ++v2) acc[u][v2] += a[u] * b[v2];
    }
    __syncthreads();
  }
#pragma unroll
  for (int u = 0; u < 4; ++u)
#pragma unroll
    for (int v2 = 0; v2 < 4; ++v2) {
      int idx = (rt * 64 + ty * 4 + u) * 64 + tx * 4 + v2;
      dst[idx] = src[idx] + acc[u][v2];
    }
}

// ---------- build Ht (rows 0..4095) and Gt (rows 4096..20479) ----------
__global__ __launch_bounds__(320) void build_hg(
    const float* __restrict__ in, const float* __restrict__ w0,
    const float* __restrict__ Kv, const float* __restrict__ P,
    unsigned short* __restrict__ Ht, unsigned short* __restrict__ Gt)
{
  int row = blockIdx.x;
  int j = threadIdx.x;
  float x;
  unsigned short* dst;
  if (row < 4096) {
    int k = row >> 6, b = row & 63;
    if (j < 64) x = in[(size_t)(k * 64 + j) * 64 + b];
    else        x = (k > 0) ? w0[((size_t)(k - 1) * 256 + (j - 64)) * 64 + b] : 0.f;
    dst = Ht + (size_t)row * 640;
  } else {
    int r2 = row - 4096;
    int i = r2 >> 8, n = r2 & 255;
    if (j < 64) x = (j <= i) ? Kv[(size_t)(i - j) * 256 + n] : 0.f;
    else        x = P[(size_t)r2 * 256 + (j - 64)];
    dst = Gt + (size_t)r2 * 640;
  }
  unsigned short hi = f2bf(x);
  float lo = x - bf2f(hi);
  dst[j]       = hi;
  dst[320 + j] = f2bf(lo);
}

// ---------- out = Ht @ Gt^T via split-bf16 MFMA; NT scatter stores ----------
__global__ __launch_bounds__(256) void out_gemm(
    const unsigned short* __restrict__ Ht,
    const unsigned short* __restrict__ Gt,
    float* __restrict__ out)
{
  __shared__ unsigned short Asm[128 * 64];
  __shared__ unsigned short Bsm[128 * 64];

  int bid = blockIdx.x;
  int swz = (bid & 7) * 512 + (bid >> 3);   // XCD swizzle (4096 % 8 == 0)
  int nt = swz >> 5;
  int mt = swz & 31;
  int mrow0 = mt * 128, nrow0 = nt * 128;

  int tid = threadIdx.x;
  int w = tid >> 6, l = tid & 63;
  int wm = w >> 1, wn = w & 1;

  char* Ab = (char*)Asm;
  char* Bb = (char*)Bsm;

  auto stage = [&](const unsigned short* src, int row0, char* lds, int k0) {
#pragma unroll
    for (int it = 0; it < 4; ++it) {
      int L = it * 4096 + tid * 16;
      int row = L >> 7;
      int p = (L >> 4) & 7;
      int o = p ^ (row & 7);
      int h = o >> 2, q = o & 3;
      const void* g = src + (size_t)(row0 + row) * 640 + h * 320 + k0 + q * 8;
      void* dst = lds + (it * 4096 + w * 1024);
      load16_lds(g, dst);
    }
  };

  stage(Ht, mrow0, Ab, 0);
  stage(Gt, nrow0, Bb, 0);

  f32x4 acc[4][4] = {};
  int rAbase = wm * 64 + (l & 15);
  int rBbase = wn * 64 + (l & 15);
  int qo = l >> 4;

  for (int ks = 0; ks < 10; ++ks) {
    __syncthreads();
    short8 ah[4], al[4], bh[4], bl[4];
#pragma unroll
    for (int mf = 0; mf < 4; ++mf) {
      int r = rAbase + mf * 16;
      int ph = (qo)     ^ (r & 7);
      int pl = (4 + qo) ^ (r & 7);
      ah[mf] = *(const short8*)(Ab + r * 128 + ph * 16);
      al[mf] = *(const short8*)(Ab + r * 128 + pl * 16);
    }
#pragma unroll
    for (int nf = 0; nf < 4; ++nf) {
      int r = rBbase + nf * 16;
      int ph = (qo)     ^ (r & 7);
      int pl = (4 + qo) ^ (r & 7);
      bh[nf] = *(const short8*)(Bb + r * 128 + ph * 16);
      bl[nf] = *(const short8*)(Bb + r * 128 + pl * 16);
    }
    __syncthreads();
    if (ks < 9) {
      stage(Ht, mrow0, Ab, (ks + 1) * 32);
      stage(Gt, nrow0, Bb, (ks + 1) * 32);
    }
#pragma unroll
    for (int mf = 0; mf < 4; ++mf)
#pragma unroll
      for (int nf = 0; nf < 4; ++nf) {
        acc[mf][nf] = __builtin_amdgcn_mfma_f32_16x16x32_bf16(ah[mf], bh[nf], acc[mf][nf], 0, 0, 0);
        acc[mf][nf] = __builtin_amdgcn_mfma_f32_16x16x32_bf16(ah[mf], bl[nf], acc[mf][nf], 0, 0, 0);
        acc[mf][nf] = __builtin_amdgcn_mfma_f32_16x16x32_bf16(al[mf], bh[nf], acc[mf][nf], 0, 0, 0);
      }
  }

  // Epilogue: direct scatter (R2-proven mapping), non-temporal scalar stores
  // -> no TCC write-allocate fetch for the 256MB output.
  int Mbase = mrow0 + wm * 64 + (l >> 4) * 4;
  int Nbase = nrow0 + wn * 64 + (l & 15);
#pragma unroll
  for (int mf = 0; mf < 4; ++mf)
#pragma unroll
    for (int nf = 0; nf < 4; ++nf)
#pragma unroll
      for (int r = 0; r < 4; ++r) {
        int Mrow = Mbase + mf * 16 + r;
        int Ncol = Nbase + nf * 16;
        int k = Mrow >> 6, b = Mrow & 63;
        int i = Ncol >> 8, n = Ncol & 255;
        __builtin_nontemporal_store(
            acc[mf][nf][r],
            &out[((size_t)k * 4096 + (size_t)i * 64 + b) * 256 + n]);
      }
}

extern "C" void kernel_launch(void* const* d_in, const int* in_sizes, int n_in,
                              void* d_out, int out_size, void* d_ws, size_t ws_size,
                              hipStream_t stream)
{
  const float* in = (const float*)d_in[0];
  const float* A  = (const float*)d_in[1];
  const float* Bv = (const float*)d_in[2];
  float* out = (float*)d_out;
  float* ws  = (float*)d_ws;

  float* P  = ws;                          // A^1..A^64
  float* Kv = P  + (size_t)64 * MATF;
  float* e  = Kv + (size_t)64 * 256;       // scan buf 0
  float* w2 = e  + (size_t)64 * 16384;     // scan buf 1
  float* MS = w2 + (size_t)64 * 16384;     // squaring ping-pong
  unsigned short* Ht = (unsigned short*)(MS + (size_t)2 * MATF);
  unsigned short* Gt = Ht + (size_t)4096 * 640;

  init_kernel<<<dim3(65), dim3(256), 0, stream>>>(A, Bv, P, Kv);

  for (int t = 0; t < 6; ++t) {
    int m = 1 << t;
    pow_round<<<dim3(m * 17), dim3(256), 0, stream>>>(P, Kv, m);
  }

  e_kernel<<<dim3(256), dim3(256), 0, stream>>>(in, Kv, e);

  float* bufs[2] = {e, w2};
  for (int r = 0; r < 6; ++r) {
    const float* M = (r == 0) ? (P + (size_t)63 * MATF)
                              : (MS + (size_t)((r - 1) & 1) * MATF);
    float* MSdst = MS + (size_t)(r & 1) * MATF;
    int grid = (r < 5) ? 272 : 256;
    scan_round<<<dim3(grid), dim3(256), 0, stream>>>(
        M, MSdst, bufs[r & 1], bufs[(r + 1) & 1], 1 << r);
  }
  // final scan result in e (round 5 writes bufs[0])

  build_hg<<<dim3(20480), dim3(320), 0, stream>>>(in, e, Kv, P, Ht, Gt);

  out_gemm<<<dim3(4096), dim3(256), 0, stream>>>(Ht, Gt, out);
}

// Round 8
// 412.000 us; speedup vs baseline: 2.1122x; 1.3304x over previous
//
#include <hip/hip_runtime.h>
#include <hip/hip_bf16.h>

// HiPPO-LegT parallel chunked scan, round 8.
// = R2 chain (measured 330us) with free-rider fusion: the 5 squarings and the
//   entire Gt build ride as extra blocks inside the 6 scan rounds (scan uses
//   only 256 blocks of 256 CUs; riders fill idle CUs; Gt needs only P+Kv).
// out_gemm is R2-verbatim (161us proven).
//
// ws layout (floats):
//   P   : A^1..A^64          (64 * 65536)
//   Kv  : A^j B, j=0..63     (64 * 256)
//   e   : scan buffer 0      (64 * 256 * 64)
//   w2  : scan buffer 1      (64 * 256 * 64)
//   MS  : squaring ping-pong (2 * 65536)
//   Ht  : bf16 [4096][640]   (hi 0..319 | lo 320..639)   (ushort)
//   Gt  : bf16 [16384][640]                               (ushort)

#define MATF 65536

typedef __attribute__((ext_vector_type(8))) short short8;
typedef __attribute__((ext_vector_type(4))) float f32x4;

__device__ __forceinline__ unsigned short f2bf(float x) {
  union { __hip_bfloat16 h; unsigned short u; } cv;
  cv.h = __float2bfloat16(x);
  return cv.u;
}
__device__ __forceinline__ float bf2f(unsigned short u) {
  union { unsigned short u; __hip_bfloat16 h; } cv;
  cv.u = u;
  return __bfloat162float(cv.h);
}

__device__ __forceinline__ void load16_lds(const void* gsrc, void* ldst) {
  __builtin_amdgcn_global_load_lds(
      (const __attribute__((address_space(1))) unsigned int*)gsrc,
      (__attribute__((address_space(3))) unsigned int*)ldst,
      16, 0, 0);
}

// ---------- batched 256x256x256 GEMM: Z[g] = X @ Y[g] (fp32, R2-verbatim) ----------
__global__ __launch_bounds__(256) void gemm_nn_batch(
    const float* __restrict__ X, const float* __restrict__ Ys,
    float* __restrict__ Zs, int count)
{
  int g    = blockIdx.x >> 4;
  int tile = blockIdx.x & 15;
  if (g >= count) return;
  const float* Y = Ys + (size_t)g * MATF;
  float*       Z = Zs + (size_t)g * MATF;
  int tr = (tile >> 2) * 64;
  int tc = (tile & 3) * 64;

  __shared__ float As[64][33];
  __shared__ float Bs[32][65];
  int tid = threadIdx.x;
  int tx = tid & 15, ty = tid >> 4;
  float acc[4][4] = {};

  for (int k0 = 0; k0 < 256; k0 += 32) {
#pragma unroll
    for (int p = 0; p < 2; ++p) {
      int idx = tid + p * 256;
      int r = idx >> 3, c4 = (idx & 7) * 4;
      float4 v = *(const float4*)(X + (size_t)(tr + r) * 256 + k0 + c4);
      As[r][c4 + 0] = v.x; As[r][c4 + 1] = v.y; As[r][c4 + 2] = v.z; As[r][c4 + 3] = v.w;
    }
#pragma unroll
    for (int p = 0; p < 2; ++p) {
      int idx = tid + p * 256;
      int r = idx >> 4, c4 = (idx & 15) * 4;
      float4 v = *(const float4*)(Y + (size_t)(k0 + r) * 256 + tc + c4);
      Bs[r][c4 + 0] = v.x; Bs[r][c4 + 1] = v.y; Bs[r][c4 + 2] = v.z; Bs[r][c4 + 3] = v.w;
    }
    __syncthreads();
#pragma unroll
    for (int kk = 0; kk < 32; ++kk) {
      float a[4], b[4];
#pragma unroll
      for (int u = 0; u < 4; ++u) a[u] = As[ty * 4 + u][kk];
#pragma unroll
      for (int v = 0; v < 4; ++v) b[v] = Bs[kk][tx * 4 + v];
#pragma unroll
      for (int u = 0; u < 4; ++u)
#pragma unroll
        for (int v = 0; v < 4; ++v) acc[u][v] += a[u] * b[v];
    }
    __syncthreads();
  }
#pragma unroll
  for (int u = 0; u < 4; ++u)
#pragma unroll
    for (int v = 0; v < 4; ++v)
      Z[(size_t)(tr + ty * 4 + u) * 256 + tc + tx * 4 + v] = acc[u][v];
}

// ---------- Kv[j] = A^j B (R2-verbatim) ----------
__global__ __launch_bounds__(256) void kv_kernel(
    const float* __restrict__ P, const float* __restrict__ Bv,
    float* __restrict__ Kv)
{
  int j = blockIdx.x;
  int n = threadIdx.x;
  __shared__ float bs[256];
  bs[n] = Bv[n];
  __syncthreads();
  if (j == 0) { Kv[n] = bs[n]; return; }
  const float* M = P + (size_t)(j - 1) * MATF;
  float acc = 0.f;
  for (int m = 0; m < 256; ++m) acc += M[(size_t)n * 256 + m] * bs[m];
  Kv[(size_t)j * 256 + n] = acc;
}

// ---------- chunk-end local states e_k[n][b] (R2-verbatim) ----------
__global__ __launch_bounds__(256) void e_kernel(
    const float* __restrict__ in, const float* __restrict__ Kv,
    float* __restrict__ e)
{
  int k = blockIdx.x >> 6;
  int b = blockIdx.x & 63;
  int n = threadIdx.x;
  __shared__ float fs[64];
  if (n < 64) fs[n] = in[(size_t)(k * 64 + n) * 64 + b];
  __syncthreads();
  float acc = 0.f;
#pragma unroll
  for (int j = 0; j < 64; ++j) acc += Kv[(size_t)j * 256 + n] * fs[63 - j];
  e[((size_t)k * 256 + n) * 64 + b] = acc;
}

// ---------- scan round (R2 internals) + riders: squaring + Gt-build slice ----
// bid <  256         : dst[k] = src[k] + M @ src[k-d]      (k=bid>>2, rt=bid&3)
// 256 <= bid < gtoff : MSdst = M @ M                        (tile = bid-256)
// bid >= gtoff       : build Gt rows gt_row0 + (bid-gtoff)
__global__ __launch_bounds__(256) void scan_round(
    const float* __restrict__ win, float* __restrict__ wout,
    const float* __restrict__ M, int d,
    float* __restrict__ MSdst,
    const float* __restrict__ P, const float* __restrict__ Kv,
    unsigned short* __restrict__ Gt, int gt_row0, int gt_off)
{
  __shared__ float As[64][33];
  __shared__ float Bs[32][65];
  int bid = blockIdx.x;
  int tid = threadIdx.x;

  if (bid >= gt_off) {
    // ---- Gt rider: row r2 = (i,n); cols: conv taps then A^{i+1} row ----
    int r2 = gt_row0 + (bid - gt_off);
    if (r2 >= 16384) return;
    int i = r2 >> 8, n = r2 & 255;
    unsigned short* dst = Gt + (size_t)r2 * 640;
    for (int c = tid; c < 320; c += 256) {
      float x;
      if (c < 64) x = (c <= i) ? Kv[(size_t)(i - c) * 256 + n] : 0.f;
      else        x = P[(size_t)i * MATF + (size_t)n * 256 + (c - 64)];
      unsigned short hi = f2bf(x);
      float lo = x - bf2f(hi);
      dst[c]       = hi;
      dst[320 + c] = f2bf(lo);
    }
    return;
  }
  if (bid >= 256) {
    // ---- squaring rider: MSdst = M @ M, tile = bid-256 ----
    int tile = bid - 256;
    int tr = (tile >> 2) * 64;
    int tc = (tile & 3) * 64;
    int tx = tid & 15, ty = tid >> 4;
    float acc[4][4] = {};
    for (int k0 = 0; k0 < 256; k0 += 32) {
#pragma unroll
      for (int p = 0; p < 2; ++p) {
        int idx = tid + p * 256;
        int r = idx >> 3, c4 = (idx & 7) * 4;
        float4 v = *(const float4*)(M + (size_t)(tr + r) * 256 + k0 + c4);
        As[r][c4 + 0] = v.x; As[r][c4 + 1] = v.y; As[r][c4 + 2] = v.z; As[r][c4 + 3] = v.w;
      }
#pragma unroll
      for (int p = 0; p < 2; ++p) {
        int idx = tid + p * 256;
        int r = idx >> 4, c4 = (idx & 15) * 4;
        float4 v = *(const float4*)(M + (size_t)(k0 + r) * 256 + tc + c4);
        Bs[r][c4 + 0] = v.x; Bs[r][c4 + 1] = v.y; Bs[r][c4 + 2] = v.z; Bs[r][c4 + 3] = v.w;
      }
      __syncthreads();
#pragma unroll
      for (int kk = 0; kk < 32; ++kk) {
        float a[4], b[4];
#pragma unroll
        for (int u = 0; u < 4; ++u) a[u] = As[ty * 4 + u][kk];
#pragma unroll
        for (int v = 0; v < 4; ++v) b[v] = Bs[kk][tx * 4 + v];
#pragma unroll
        for (int u = 0; u < 4; ++u)
#pragma unroll
          for (int v = 0; v < 4; ++v) acc[u][v] += a[u] * b[v];
      }
      __syncthreads();
    }
#pragma unroll
    for (int u = 0; u < 4; ++u)
#pragma unroll
      for (int v = 0; v < 4; ++v)
        MSdst[(size_t)(tr + ty * 4 + u) * 256 + tc + tx * 4 + v] = acc[u][v];
    return;
  }

  // ---- scan (R2-verbatim) ----
  int k  = bid >> 2;
  int rt = bid & 3;
  const float* src = win  + (size_t)k * 16384;
  float*       dst = wout + (size_t)k * 16384;
  if (k < d) {
#pragma unroll
    for (int p = 0; p < 16; ++p) {
      int idx = rt * 4096 + p * 256 + tid;
      dst[idx] = src[idx];
    }
    return;
  }
  const float* v = win + (size_t)(k - d) * 16384;
  int tx = tid & 15, ty = tid >> 4;
  float acc[4][4] = {};
  for (int k0 = 0; k0 < 256; k0 += 32) {
#pragma unroll
    for (int p = 0; p < 2; ++p) {
      int idx = tid + p * 256;
      int r = idx >> 3, c4 = (idx & 7) * 4;
      float4 t4 = *(const float4*)(M + (size_t)(rt * 64 + r) * 256 + k0 + c4);
      As[r][c4 + 0] = t4.x; As[r][c4 + 1] = t4.y; As[r][c4 + 2] = t4.z; As[r][c4 + 3] = t4.w;
    }
#pragma unroll
    for (int p = 0; p < 2; ++p) {
      int idx = tid + p * 256;
      int r = idx >> 4, c4 = (idx & 15) * 4;
      float4 t4 = *(const float4*)(v + (size_t)(k0 + r) * 64 + c4);
      Bs[r][c4 + 0] = t4.x; Bs[r][c4 + 1] = t4.y; Bs[r][c4 + 2] = t4.z; Bs[r][c4 + 3] = t4.w;
    }
    __syncthreads();
#pragma unroll
    for (int kk = 0; kk < 32; ++kk) {
      float a[4], b[4];
#pragma unroll
      for (int u = 0; u < 4; ++u) a[u] = As[ty * 4 + u][kk];
#pragma unroll
      for (int v2 = 0; v2 < 4; ++v2) b[v2] = Bs[kk][tx * 4 + v2];
#pragma unroll
      for (int u = 0; u < 4; ++u)
#pragma unroll
        for (int v2 = 0; v2 < 4; ++v2) acc[u][v2] += a[u] * b[v2];
    }
    __syncthreads();
  }
#pragma unroll
  for (int u = 0; u < 4; ++u)
#pragma unroll
    for (int v2 = 0; v2 < 4; ++v2) {
      int idx = (rt * 64 + ty * 4 + u) * 64 + tx * 4 + v2;
      dst[idx] = src[idx] + acc[u][v2];
    }
}

// ---------- build Ht: [4096 rows (k,b)][hi 320 | lo 320] (R2-verbatim) ----------
__global__ __launch_bounds__(320) void build_ht(
    const float* __restrict__ in, const float* __restrict__ w,
    unsigned short* __restrict__ Ht)
{
  int row = blockIdx.x;
  int k = row >> 6, b = row & 63;
  int j = threadIdx.x;
  float x;
  if (j < 64) x = in[(size_t)(k * 64 + j) * 64 + b];
  else        x = (k > 0) ? w[((size_t)(k - 1) * 256 + (j - 64)) * 64 + b] : 0.f;
  unsigned short hi = f2bf(x);
  float lo = x - bf2f(hi);
  Ht[(size_t)row * 640 + j]       = hi;
  Ht[(size_t)row * 640 + 320 + j] = f2bf(lo);
}

// ---------- out = Ht @ Gt^T via split-bf16 MFMA (R2-verbatim) ----------
__global__ __launch_bounds__(256) void out_gemm(
    const unsigned short* __restrict__ Ht,
    const unsigned short* __restrict__ Gt,
    float* __restrict__ out)
{
  __shared__ unsigned short Asm[128 * 64];
  __shared__ unsigned short Bsm[128 * 64];

  int bid = blockIdx.x;
  int swz = (bid & 7) * 512 + (bid >> 3);
  int nt = swz >> 5;
  int mt = swz & 31;
  int mrow0 = mt * 128, nrow0 = nt * 128;

  int tid = threadIdx.x;
  int w = tid >> 6, l = tid & 63;
  int wm = w >> 1, wn = w & 1;

  char* Ab = (char*)Asm;
  char* Bb = (char*)Bsm;

  auto stage = [&](const unsigned short* src, int row0, char* lds, int k0) {
#pragma unroll
    for (int it = 0; it < 4; ++it) {
      int L = it * 4096 + tid * 16;
      int row = L >> 7;
      int p = (L >> 4) & 7;
      int o = p ^ (row & 7);
      int h = o >> 2, q = o & 3;
      const void* g = src + (size_t)(row0 + row) * 640 + h * 320 + k0 + q * 8;
      void* dst = lds + (it * 4096 + w * 1024);
      load16_lds(g, dst);
    }
  };

  stage(Ht, mrow0, Ab, 0);
  stage(Gt, nrow0, Bb, 0);

  f32x4 acc[4][4] = {};
  int rAbase = wm * 64 + (l & 15);
  int rBbase = wn * 64 + (l & 15);
  int qo = l >> 4;

  for (int ks = 0; ks < 10; ++ks) {
    __syncthreads();
    short8 ah[4], al[4], bh[4], bl[4];
#pragma unroll
    for (int mf = 0; mf < 4; ++mf) {
      int r = rAbase + mf * 16;
      int ph = (qo)     ^ (r & 7);
      int pl = (4 + qo) ^ (r & 7);
      ah[mf] = *(const short8*)(Ab + r * 128 + ph * 16);
      al[mf] = *(const short8*)(Ab + r * 128 + pl * 16);
    }
#pragma unroll
    for (int nf = 0; nf < 4; ++nf) {
      int r = rBbase + nf * 16;
      int ph = (qo)     ^ (r & 7);
      int pl = (4 + qo) ^ (r & 7);
      bh[nf] = *(const short8*)(Bb + r * 128 + ph * 16);
      bl[nf] = *(const short8*)(Bb + r * 128 + pl * 16);
    }
    __syncthreads();
    if (ks < 9) {
      stage(Ht, mrow0, Ab, (ks + 1) * 32);
      stage(Gt, nrow0, Bb, (ks + 1) * 32);
    }
#pragma unroll
    for (int mf = 0; mf < 4; ++mf)
#pragma unroll
      for (int nf = 0; nf < 4; ++nf) {
        acc[mf][nf] = __builtin_amdgcn_mfma_f32_16x16x32_bf16(ah[mf], bh[nf], acc[mf][nf], 0, 0, 0);
        acc[mf][nf] = __builtin_amdgcn_mfma_f32_16x16x32_bf16(ah[mf], bl[nf], acc[mf][nf], 0, 0, 0);
        acc[mf][nf] = __builtin_amdgcn_mfma_f32_16x16x32_bf16(al[mf], bh[nf], acc[mf][nf], 0, 0, 0);
      }
  }

  int Mbase = mrow0 + wm * 64 + (l >> 4) * 4;
  int Nbase = nrow0 + wn * 64 + (l & 15);
#pragma unroll
  for (int mf = 0; mf < 4; ++mf)
#pragma unroll
    for (int nf = 0; nf < 4; ++nf)
#pragma unroll
      for (int r = 0; r < 4; ++r) {
        int Mrow = Mbase + mf * 16 + r;
        int Ncol = Nbase + nf * 16;
        int k = Mrow >> 6, b = Mrow & 63;
        int i = Ncol >> 8, n = Ncol & 255;
        out[((size_t)k * 4096 + (size_t)i * 64 + b) * 256 + n] = acc[mf][nf][r];
      }
}

extern "C" void kernel_launch(void* const* d_in, const int* in_sizes, int n_in,
                              void* d_out, int out_size, void* d_ws, size_t ws_size,
                              hipStream_t stream)
{
  const float* in = (const float*)d_in[0];
  const float* A  = (const float*)d_in[1];
  const float* Bv = (const float*)d_in[2];
  float* out = (float*)d_out;
  float* ws  = (float*)d_ws;

  float* P  = ws;                          // A^1..A^64
  float* Kv = P  + (size_t)64 * MATF;
  float* e  = Kv + (size_t)64 * 256;       // scan buf 0
  float* w2 = e  + (size_t)64 * 16384;     // scan buf 1
  float* MS = w2 + (size_t)64 * 16384;     // squaring ping-pong
  unsigned short* Ht = (unsigned short*)(MS + (size_t)2 * MATF);
  unsigned short* Gt = Ht + (size_t)4096 * 640;

  hipMemcpyAsync(P, A, (size_t)MATF * sizeof(float),
                 hipMemcpyDeviceToDevice, stream);
  // log-doubling: P_{m+j} = P_m @ P_j, j=1..m
  for (int m = 1; m <= 32; m <<= 1) {
    gemm_nn_batch<<<dim3(m * 16), dim3(256), 0, stream>>>(
        P + (size_t)(m - 1) * MATF, P, P + (size_t)m * MATF, m);
  }
  kv_kernel<<<dim3(64), dim3(256), 0, stream>>>(P, Bv, Kv);
  e_kernel<<<dim3(4096), dim3(256), 0, stream>>>(in, Kv, e);

  // 6 scan rounds; riders: squaring M_{r+1}=M_r^2 (r<5) + Gt rows (2731/round)
  float* bufs[2] = {e, w2};
  for (int r = 0; r < 6; ++r) {
    const float* M = (r == 0) ? (P + (size_t)63 * MATF)
                              : (MS + (size_t)((r - 1) & 1) * MATF);
    float* MSdst = MS + (size_t)(r & 1) * MATF;
    int gt_row0 = r * 2731;
    int gt_cnt  = (r < 5) ? 2731 : (16384 - 5 * 2731);
    int gt_off  = (r < 5) ? 272 : 256;
    int grid    = gt_off + gt_cnt;
    scan_round<<<dim3(grid), dim3(256), 0, stream>>>(
        bufs[r & 1], bufs[(r + 1) & 1], M, 1 << r,
        MSdst, P, Kv, Gt, gt_row0, gt_off);
  }
  // final scan result in e (round 5 writes bufs[0])

  build_ht<<<dim3(4096), dim3(320), 0, stream>>>(in, e, Ht);

  out_gemm<<<dim3(4096), dim3(256), 0, stream>>>(Ht, Gt, out);
}

// Round 9
// 404.838 us; speedup vs baseline: 2.1496x; 1.0177x over previous
//
#include <hip/hip_runtime.h>
#include <hip/hip_bf16.h>

// HiPPO-LegT parallel chunked scan, round 9.
// = R8 chain (proven ~250us) minus the memcpy dispatch (P1 copy rides on the
//   first pow round, which reads input A directly), plus a double-buffered
//   2-phase out_gemm: stage(next) issued BEFORE ds_read(cur), ONE barrier per
//   K-step -> global_load_lds latency hidden under a full iteration.
//
// ws layout (floats):
//   P   : A^1..A^64          (64 * 65536)
//   Kv  : A^j B, j=0..63     (64 * 256)
//   e   : scan buffer 0      (64 * 256 * 64)
//   w2  : scan buffer 1      (64 * 256 * 64)
//   MS  : squaring ping-pong (2 * 65536)
//   Ht  : bf16 [4096][640]   (hi 0..319 | lo 320..639)   (ushort)
//   Gt  : bf16 [16384][640]                               (ushort)

#define MATF 65536

typedef __attribute__((ext_vector_type(8))) short short8;
typedef __attribute__((ext_vector_type(4))) float f32x4;

__device__ __forceinline__ unsigned short f2bf(float x) {
  union { __hip_bfloat16 h; unsigned short u; } cv;
  cv.h = __float2bfloat16(x);
  return cv.u;
}
__device__ __forceinline__ float bf2f(unsigned short u) {
  union { unsigned short u; __hip_bfloat16 h; } cv;
  cv.u = u;
  return __bfloat162float(cv.h);
}

__device__ __forceinline__ void load16_lds(const void* gsrc, void* ldst) {
  __builtin_amdgcn_global_load_lds(
      (const __attribute__((address_space(1))) unsigned int*)gsrc,
      (__attribute__((address_space(3))) unsigned int*)ldst,
      16, 0, 0);
}

// ---------- batched 256x256x256 GEMM: Z[g] = X @ Y[g] (fp32) ----------
__global__ __launch_bounds__(256) void gemm_nn_batch(
    const float* __restrict__ X, const float* __restrict__ Ys,
    float* __restrict__ Zs, int count)
{
  int g    = blockIdx.x >> 4;
  int tile = blockIdx.x & 15;
  if (g >= count) return;
  const float* Y = Ys + (size_t)g * MATF;
  float*       Z = Zs + (size_t)g * MATF;
  int tr = (tile >> 2) * 64;
  int tc = (tile & 3) * 64;

  __shared__ float As[64][33];
  __shared__ float Bs[32][65];
  int tid = threadIdx.x;
  int tx = tid & 15, ty = tid >> 4;
  float acc[4][4] = {};

  for (int k0 = 0; k0 < 256; k0 += 32) {
#pragma unroll
    for (int p = 0; p < 2; ++p) {
      int idx = tid + p * 256;
      int r = idx >> 3, c4 = (idx & 7) * 4;
      float4 v = *(const float4*)(X + (size_t)(tr + r) * 256 + k0 + c4);
      As[r][c4 + 0] = v.x; As[r][c4 + 1] = v.y; As[r][c4 + 2] = v.z; As[r][c4 + 3] = v.w;
    }
#pragma unroll
    for (int p = 0; p < 2; ++p) {
      int idx = tid + p * 256;
      int r = idx >> 4, c4 = (idx & 15) * 4;
      float4 v = *(const float4*)(Y + (size_t)(k0 + r) * 256 + tc + c4);
      Bs[r][c4 + 0] = v.x; Bs[r][c4 + 1] = v.y; Bs[r][c4 + 2] = v.z; Bs[r][c4 + 3] = v.w;
    }
    __syncthreads();
#pragma unroll
    for (int kk = 0; kk < 32; ++kk) {
      float a[4], b[4];
#pragma unroll
      for (int u = 0; u < 4; ++u) a[u] = As[ty * 4 + u][kk];
#pragma unroll
      for (int v = 0; v < 4; ++v) b[v] = Bs[kk][tx * 4 + v];
#pragma unroll
      for (int u = 0; u < 4; ++u)
#pragma unroll
        for (int v = 0; v < 4; ++v) acc[u][v] += a[u] * b[v];
    }
    __syncthreads();
  }
#pragma unroll
  for (int u = 0; u < 4; ++u)
#pragma unroll
    for (int v = 0; v < 4; ++v)
      Z[(size_t)(tr + ty * 4 + u) * 256 + tc + tx * 4 + v] = acc[u][v];
}

// ---------- first pow round: P_2 = A@A (blocks 0..15) ; P_1 = A (16..31) ----
__global__ __launch_bounds__(256) void pow_first(
    const float* __restrict__ A, float* __restrict__ P)
{
  int bid = blockIdx.x, tid = threadIdx.x;
  if (bid >= 16) {
    int blk = bid - 16;
#pragma unroll
    for (int q = 0; q < 4; ++q) {
      int idx = blk * 1024 + q * 256 + tid;
      *(float4*)(P + (size_t)idx * 4) = *(const float4*)(A + (size_t)idx * 4);
    }
    return;
  }
  int tile = bid;
  int tr = (tile >> 2) * 64;
  int tc = (tile & 3) * 64;
  __shared__ float As[64][33];
  __shared__ float Bs[32][65];
  int tx = tid & 15, ty = tid >> 4;
  float acc[4][4] = {};
  for (int k0 = 0; k0 < 256; k0 += 32) {
#pragma unroll
    for (int p = 0; p < 2; ++p) {
      int idx = tid + p * 256;
      int r = idx >> 3, c4 = (idx & 7) * 4;
      float4 v = *(const float4*)(A + (size_t)(tr + r) * 256 + k0 + c4);
      As[r][c4 + 0] = v.x; As[r][c4 + 1] = v.y; As[r][c4 + 2] = v.z; As[r][c4 + 3] = v.w;
    }
#pragma unroll
    for (int p = 0; p < 2; ++p) {
      int idx = tid + p * 256;
      int r = idx >> 4, c4 = (idx & 15) * 4;
      float4 v = *(const float4*)(A + (size_t)(k0 + r) * 256 + tc + c4);
      Bs[r][c4 + 0] = v.x; Bs[r][c4 + 1] = v.y; Bs[r][c4 + 2] = v.z; Bs[r][c4 + 3] = v.w;
    }
    __syncthreads();
#pragma unroll
    for (int kk = 0; kk < 32; ++kk) {
      float a[4], b[4];
#pragma unroll
      for (int u = 0; u < 4; ++u) a[u] = As[ty * 4 + u][kk];
#pragma unroll
      for (int v = 0; v < 4; ++v) b[v] = Bs[kk][tx * 4 + v];
#pragma unroll
      for (int u = 0; u < 4; ++u)
#pragma unroll
        for (int v = 0; v < 4; ++v) acc[u][v] += a[u] * b[v];
    }
    __syncthreads();
  }
#pragma unroll
  for (int u = 0; u < 4; ++u)
#pragma unroll
    for (int v = 0; v < 4; ++v)
      P[(size_t)MATF + (size_t)(tr + ty * 4 + u) * 256 + tc + tx * 4 + v] = acc[u][v];
}

// ---------- Kv[j] = A^j B ----------
__global__ __launch_bounds__(256) void kv_kernel(
    const float* __restrict__ P, const float* __restrict__ Bv,
    float* __restrict__ Kv)
{
  int j = blockIdx.x;
  int n = threadIdx.x;
  __shared__ float bs[256];
  bs[n] = Bv[n];
  __syncthreads();
  if (j == 0) { Kv[n] = bs[n]; return; }
  const float* M = P + (size_t)(j - 1) * MATF;
  float acc = 0.f;
  for (int m = 0; m < 256; ++m) acc += M[(size_t)n * 256 + m] * bs[m];
  Kv[(size_t)j * 256 + n] = acc;
}

// ---------- chunk-end local states e_k[n][b] ----------
__global__ __launch_bounds__(256) void e_kernel(
    const float* __restrict__ in, const float* __restrict__ Kv,
    float* __restrict__ e)
{
  int k = blockIdx.x >> 6;
  int b = blockIdx.x & 63;
  int n = threadIdx.x;
  __shared__ float fs[64];
  if (n < 64) fs[n] = in[(size_t)(k * 64 + n) * 64 + b];
  __syncthreads();
  float acc = 0.f;
#pragma unroll
  for (int j = 0; j < 64; ++j) acc += Kv[(size_t)j * 256 + n] * fs[63 - j];
  e[((size_t)k * 256 + n) * 64 + b] = acc;
}

// ---------- scan round + riders: squaring + Gt-build slice (R8-verbatim) ----
__global__ __launch_bounds__(256) void scan_round(
    const float* __restrict__ win, float* __restrict__ wout,
    const float* __restrict__ M, int d,
    float* __restrict__ MSdst,
    const float* __restrict__ P, const float* __restrict__ Kv,
    unsigned short* __restrict__ Gt, int gt_row0, int gt_off)
{
  __shared__ float As[64][33];
  __shared__ float Bs[32][65];
  int bid = blockIdx.x;
  int tid = threadIdx.x;

  if (bid >= gt_off) {
    int r2 = gt_row0 + (bid - gt_off);
    if (r2 >= 16384) return;
    int i = r2 >> 8, n = r2 & 255;
    unsigned short* dst = Gt + (size_t)r2 * 640;
    for (int c = tid; c < 320; c += 256) {
      float x;
      if (c < 64) x = (c <= i) ? Kv[(size_t)(i - c) * 256 + n] : 0.f;
      else        x = P[(size_t)i * MATF + (size_t)n * 256 + (c - 64)];
      unsigned short hi = f2bf(x);
      float lo = x - bf2f(hi);
      dst[c]       = hi;
      dst[320 + c] = f2bf(lo);
    }
    return;
  }
  if (bid >= 256) {
    int tile = bid - 256;
    int tr = (tile >> 2) * 64;
    int tc = (tile & 3) * 64;
    int tx = tid & 15, ty = tid >> 4;
    float acc[4][4] = {};
    for (int k0 = 0; k0 < 256; k0 += 32) {
#pragma unroll
      for (int p = 0; p < 2; ++p) {
        int idx = tid + p * 256;
        int r = idx >> 3, c4 = (idx & 7) * 4;
        float4 v = *(const float4*)(M + (size_t)(tr + r) * 256 + k0 + c4);
        As[r][c4 + 0] = v.x; As[r][c4 + 1] = v.y; As[r][c4 + 2] = v.z; As[r][c4 + 3] = v.w;
      }
#pragma unroll
      for (int p = 0; p < 2; ++p) {
        int idx = tid + p * 256;
        int r = idx >> 4, c4 = (idx & 15) * 4;
        float4 v = *(const float4*)(M + (size_t)(k0 + r) * 256 + tc + c4);
        Bs[r][c4 + 0] = v.x; Bs[r][c4 + 1] = v.y; Bs[r][c4 + 2] = v.z; Bs[r][c4 + 3] = v.w;
      }
      __syncthreads();
#pragma unroll
      for (int kk = 0; kk < 32; ++kk) {
        float a[4], b[4];
#pragma unroll
        for (int u = 0; u < 4; ++u) a[u] = As[ty * 4 + u][kk];
#pragma unroll
        for (int v = 0; v < 4; ++v) b[v] = Bs[kk][tx * 4 + v];
#pragma unroll
        for (int u = 0; u < 4; ++u)
#pragma unroll
          for (int v = 0; v < 4; ++v) acc[u][v] += a[u] * b[v];
      }
      __syncthreads();
    }
#pragma unroll
    for (int u = 0; u < 4; ++u)
#pragma unroll
      for (int v = 0; v < 4; ++v)
        MSdst[(size_t)(tr + ty * 4 + u) * 256 + tc + tx * 4 + v] = acc[u][v];
    return;
  }

  int k  = bid >> 2;
  int rt = bid & 3;
  const float* src = win  + (size_t)k * 16384;
  float*       dst = wout + (size_t)k * 16384;
  if (k < d) {
#pragma unroll
    for (int p = 0; p < 16; ++p) {
      int idx = rt * 4096 + p * 256 + tid;
      dst[idx] = src[idx];
    }
    return;
  }
  const float* v = win + (size_t)(k - d) * 16384;
  int tx = tid & 15, ty = tid >> 4;
  float acc[4][4] = {};
  for (int k0 = 0; k0 < 256; k0 += 32) {
#pragma unroll
    for (int p = 0; p < 2; ++p) {
      int idx = tid + p * 256;
      int r = idx >> 3, c4 = (idx & 7) * 4;
      float4 t4 = *(const float4*)(M + (size_t)(rt * 64 + r) * 256 + k0 + c4);
      As[r][c4 + 0] = t4.x; As[r][c4 + 1] = t4.y; As[r][c4 + 2] = t4.z; As[r][c4 + 3] = t4.w;
    }
#pragma unroll
    for (int p = 0; p < 2; ++p) {
      int idx = tid + p * 256;
      int r = idx >> 4, c4 = (idx & 15) * 4;
      float4 t4 = *(const float4*)(v + (size_t)(k0 + r) * 64 + c4);
      Bs[r][c4 + 0] = t4.x; Bs[r][c4 + 1] = t4.y; Bs[r][c4 + 2] = t4.z; Bs[r][c4 + 3] = t4.w;
    }
    __syncthreads();
#pragma unroll
    for (int kk = 0; kk < 32; ++kk) {
      float a[4], b[4];
#pragma unroll
      for (int u = 0; u < 4; ++u) a[u] = As[ty * 4 + u][kk];
#pragma unroll
      for (int v2 = 0; v2 < 4; ++v2) b[v2] = Bs[kk][tx * 4 + v2];
#pragma unroll
      for (int u = 0; u < 4; ++u)
#pragma unroll
        for (int v2 = 0; v2 < 4; ++v2) acc[u][v2] += a[u] * b[v2];
    }
    __syncthreads();
  }
#pragma unroll
  for (int u = 0; u < 4; ++u)
#pragma unroll
    for (int v2 = 0; v2 < 4; ++v2) {
      int idx = (rt * 64 + ty * 4 + u) * 64 + tx * 4 + v2;
      dst[idx] = src[idx] + acc[u][v2];
    }
}

// ---------- build Ht ----------
__global__ __launch_bounds__(320) void build_ht(
    const float* __restrict__ in, const float* __restrict__ w,
    unsigned short* __restrict__ Ht)
{
  int row = blockIdx.x;
  int k = row >> 6, b = row & 63;
  int j = threadIdx.x;
  float x;
  if (j < 64) x = in[(size_t)(k * 64 + j) * 64 + b];
  else        x = (k > 0) ? w[((size_t)(k - 1) * 256 + (j - 64)) * 64 + b] : 0.f;
  unsigned short hi = f2bf(x);
  float lo = x - bf2f(hi);
  Ht[(size_t)row * 640 + j]       = hi;
  Ht[(size_t)row * 640 + 320 + j] = f2bf(lo);
}

// ---------- out = Ht @ Gt^T, split-bf16 MFMA, DOUBLE-BUFFERED 2-phase ----------
// LDS: 2 bufs x (A 16KB | B 16KB) = 64KB. Per K-step: stage(next) FIRST,
// then ds_read(cur) + MFMA, then ONE barrier (its implicit vmcnt(0) drain
// lands a full iteration after issue -> HBM latency hidden).
__global__ __launch_bounds__(256) void out_gemm(
    const unsigned short* __restrict__ Ht,
    const unsigned short* __restrict__ Gt,
    float* __restrict__ out)
{
  __shared__ char smem[65536];

  int bid = blockIdx.x;
  int swz = (bid & 7) * 512 + (bid >> 3);   // XCD swizzle (4096 % 8 == 0)
  int nt = swz >> 5;
  int mt = swz & 31;
  int mrow0 = mt * 128, nrow0 = nt * 128;

  int tid = threadIdx.x;
  int w = tid >> 6, l = tid & 63;
  int wm = w >> 1, wn = w & 1;

  auto stage = [&](const unsigned short* src, int row0, char* lds, int k0) {
#pragma unroll
    for (int it = 0; it < 4; ++it) {
      int L = it * 4096 + tid * 16;
      int row = L >> 7;
      int p = (L >> 4) & 7;
      int o = p ^ (row & 7);
      int h = o >> 2, q = o & 3;
      const void* g = src + (size_t)(row0 + row) * 640 + h * 320 + k0 + q * 8;
      void* dst = lds + (it * 4096 + w * 1024);
      load16_lds(g, dst);
    }
  };

  stage(Ht, mrow0, smem, 0);
  stage(Gt, nrow0, smem + 16384, 0);
  __syncthreads();   // implicit vmcnt(0): buf0 ready

  f32x4 acc[4][4] = {};
  int rAbase = wm * 64 + (l & 15);
  int rBbase = wn * 64 + (l & 15);
  int qo = l >> 4;

  for (int ks = 0; ks < 10; ++ks) {
    char* cur = smem + (ks & 1) * 32768;
    if (ks < 9) {
      char* nxt = smem + ((ks + 1) & 1) * 32768;
      stage(Ht, mrow0, nxt, (ks + 1) * 32);
      stage(Gt, nrow0, nxt + 16384, (ks + 1) * 32);
    }
    char* Ab = cur;
    char* Bb = cur + 16384;
    short8 ah[4], al[4], bh[4], bl[4];
#pragma unroll
    for (int mf = 0; mf < 4; ++mf) {
      int r = rAbase + mf * 16;
      int ph = (qo)     ^ (r & 7);
      int pl = (4 + qo) ^ (r & 7);
      ah[mf] = *(const short8*)(Ab + r * 128 + ph * 16);
      al[mf] = *(const short8*)(Ab + r * 128 + pl * 16);
    }
#pragma unroll
    for (int nf = 0; nf < 4; ++nf) {
      int r = rBbase + nf * 16;
      int ph = (qo)     ^ (r & 7);
      int pl = (4 + qo) ^ (r & 7);
      bh[nf] = *(const short8*)(Bb + r * 128 + ph * 16);
      bl[nf] = *(const short8*)(Bb + r * 128 + pl * 16);
    }
#pragma unroll
    for (int mf = 0; mf < 4; ++mf)
#pragma unroll
      for (int nf = 0; nf < 4; ++nf) {
        acc[mf][nf] = __builtin_amdgcn_mfma_f32_16x16x32_bf16(ah[mf], bh[nf], acc[mf][nf], 0, 0, 0);
        acc[mf][nf] = __builtin_amdgcn_mfma_f32_16x16x32_bf16(ah[mf], bl[nf], acc[mf][nf], 0, 0, 0);
        acc[mf][nf] = __builtin_amdgcn_mfma_f32_16x16x32_bf16(al[mf], bh[nf], acc[mf][nf], 0, 0, 0);
      }
    // one barrier per K-step: all waves' ds_reads of cur done (MFMA consumed
    // them) AND this iter's stage into nxt drained (compiler vmcnt(0)).
    __syncthreads();
  }

  int Mbase = mrow0 + wm * 64 + (l >> 4) * 4;
  int Nbase = nrow0 + wn * 64 + (l & 15);
#pragma unroll
  for (int mf = 0; mf < 4; ++mf)
#pragma unroll
    for (int nf = 0; nf < 4; ++nf)
#pragma unroll
      for (int r = 0; r < 4; ++r) {
        int Mrow = Mbase + mf * 16 + r;
        int Ncol = Nbase + nf * 16;
        int k = Mrow >> 6, b = Mrow & 63;
        int i = Ncol >> 8, n = Ncol & 255;
        out[((size_t)k * 4096 + (size_t)i * 64 + b) * 256 + n] = acc[mf][nf][r];
      }
}

extern "C" void kernel_launch(void* const* d_in, const int* in_sizes, int n_in,
                              void* d_out, int out_size, void* d_ws, size_t ws_size,
                              hipStream_t stream)
{
  const float* in = (const float*)d_in[0];
  const float* A  = (const float*)d_in[1];
  const float* Bv = (const float*)d_in[2];
  float* out = (float*)d_out;
  float* ws  = (float*)d_ws;

  float* P  = ws;                          // A^1..A^64
  float* Kv = P  + (size_t)64 * MATF;
  float* e  = Kv + (size_t)64 * 256;       // scan buf 0
  float* w2 = e  + (size_t)64 * 16384;     // scan buf 1
  float* MS = w2 + (size_t)64 * 16384;     // squaring ping-pong
  unsigned short* Ht = (unsigned short*)(MS + (size_t)2 * MATF);
  unsigned short* Gt = Ht + (size_t)4096 * 640;

  // round m=1: P_2 = A@A + rider copy P_1 = A (replaces memcpy dispatch)
  pow_first<<<dim3(32), dim3(256), 0, stream>>>(A, P);
  // log-doubling rounds m=2..32: P_{m+j} = P_m @ P_j, j=1..m
  for (int m = 2; m <= 32; m <<= 1) {
    gemm_nn_batch<<<dim3(m * 16), dim3(256), 0, stream>>>(
        P + (size_t)(m - 1) * MATF, P, P + (size_t)m * MATF, m);
  }
  kv_kernel<<<dim3(64), dim3(256), 0, stream>>>(P, Bv, Kv);
  e_kernel<<<dim3(4096), dim3(256), 0, stream>>>(in, Kv, e);

  // 6 scan rounds; riders: squaring M_{r+1}=M_r^2 (r<5) + Gt rows (2731/round)
  float* bufs[2] = {e, w2};
  for (int r = 0; r < 6; ++r) {
    const float* M = (r == 0) ? (P + (size_t)63 * MATF)
                              : (MS + (size_t)((r - 1) & 1) * MATF);
    float* MSdst = MS + (size_t)(r & 1) * MATF;
    int gt_row0 = r * 2731;
    int gt_cnt  = (r < 5) ? 2731 : (16384 - 5 * 2731);
    int gt_off  = (r < 5) ? 272 : 256;
    int grid    = gt_off + gt_cnt;
    scan_round<<<dim3(grid), dim3(256), 0, stream>>>(
        bufs[r & 1], bufs[(r + 1) & 1], M, 1 << r,
        MSdst, P, Kv, Gt, gt_row0, gt_off);
  }
  // final scan result in e (round 5 writes bufs[0])

  build_ht<<<dim3(4096), dim3(320), 0, stream>>>(in, e, Ht);

  out_gemm<<<dim3(4096), dim3(256), 0, stream>>>(Ht, Gt, out);
}